// Round 6
// baseline (409.626 us; speedup 1.0000x reference)
//
#include <hip/hip_runtime.h>
#include <math.h>

namespace {

constexpr int kT = 1024;
constexpr int kH = 1024;
constexpr int kNQ = 16;
constexpr int kNKV = 4;
constexpr int kD = 64;
constexpr int kQKV = (kNQ + 2 * kNKV) * kD;   // 1536
constexpr int kIDense = 4096;
constexpr int kIMoe = 512;
constexpr int kE = 8;
constexpr float kEps = 1e-6f;

typedef __attribute__((ext_vector_type(8))) short short8;
typedef __attribute__((ext_vector_type(4))) float f32x4;

__device__ __forceinline__ ushort f2bf(float f) {
    union { float f; uint32_t u; } v; v.f = f;
    uint32_t r = (v.u + 0x7fffu + ((v.u >> 16) & 1u)) >> 16;
    return (ushort)r;
}
__device__ __forceinline__ float f4el(const float4& v, int i) {
    return (i == 0) ? v.x : (i == 1) ? v.y : (i == 2) ? v.z : v.w;
}
__device__ __forceinline__ void gload16(const void* g, void* l) {
    __builtin_amdgcn_global_load_lds(
        (const __attribute__((address_space(1))) void*)g,
        (__attribute__((address_space(3))) void*)l, 16, 0, 0);
}

// ---------------------------------------------------------------------------
// add + RMSNorm: r_out = x + res; h = rmsnorm(r_out)*w  -> h32 (f32) + h16 (bf16)
// ---------------------------------------------------------------------------
__global__ __launch_bounds__(256) void add_rmsnorm_kernel(
    const float* __restrict__ x, const float* __restrict__ res,
    const float* __restrict__ w, float* __restrict__ h32,
    ushort* __restrict__ h16, float* __restrict__ r_out)
{
    __shared__ float red[4];
    const int t = blockIdx.x;
    const int i = threadIdx.x;
    const size_t base = (size_t)t * kH;
    float4 a = reinterpret_cast<const float4*>(x + base)[i];
    float4 b = reinterpret_cast<const float4*>(res + base)[i];
    float4 s = make_float4(a.x + b.x, a.y + b.y, a.z + b.z, a.w + b.w);
    reinterpret_cast<float4*>(r_out + base)[i] = s;
    float ss = s.x * s.x + s.y * s.y + s.z * s.z + s.w * s.w;
    #pragma unroll
    for (int off = 32; off > 0; off >>= 1) ss += __shfl_down(ss, off);
    if ((i & 63) == 0) red[i >> 6] = ss;
    __syncthreads();
    const float tot = red[0] + red[1] + red[2] + red[3];
    const float inv = rsqrtf(tot * (1.0f / kH) + kEps);
    float4 wv = reinterpret_cast<const float4*>(w)[i];
    float4 o = make_float4(s.x * inv * wv.x, s.y * inv * wv.y,
                           s.z * inv * wv.z, s.w * inv * wv.w);
    reinterpret_cast<float4*>(h32 + base)[i] = o;
    ushort4 u;
    u.x = f2bf(o.x); u.y = f2bf(o.y); u.z = f2bf(o.z); u.w = f2bf(o.w);
    reinterpret_cast<ushort4*>(h16 + base)[i] = u;
}

// ---------------------------------------------------------------------------
// transpose + f32 -> bf16 (used only for attention V^T)
// ---------------------------------------------------------------------------
__global__ __launch_bounds__(256) void transpose_bf16_kernel(
    const float* __restrict__ W, ushort* __restrict__ WT,
    int R, int Cn, int ld_w, long w_z_stride, long wt_z_stride)
{
    __shared__ float tile[64][65];
    const int z = blockIdx.z;
    const float* Wz = W + (size_t)z * w_z_stride;
    ushort* WTz = WT + (size_t)z * wt_z_stride;
    const int r0 = blockIdx.y * 64;
    const int c0 = blockIdx.x * 64;
    const int tr = threadIdx.x >> 4;
    const int tc4 = (threadIdx.x & 15) * 4;
    #pragma unroll
    for (int p = 0; p < 4; p++) {
        float4 v = *reinterpret_cast<const float4*>(
            &Wz[(size_t)(r0 + p * 16 + tr) * ld_w + c0 + tc4]);
        tile[p * 16 + tr][tc4 + 0] = v.x;
        tile[p * 16 + tr][tc4 + 1] = v.y;
        tile[p * 16 + tr][tc4 + 2] = v.z;
        tile[p * 16 + tr][tc4 + 3] = v.w;
    }
    __syncthreads();
    #pragma unroll
    for (int p = 0; p < 4; p++) {
        const int oc = p * 16 + tr;
        ushort4 u;
        u.x = f2bf(tile[tc4 + 0][oc]);
        u.y = f2bf(tile[tc4 + 1][oc]);
        u.z = f2bf(tile[tc4 + 2][oc]);
        u.w = f2bf(tile[tc4 + 3][oc]);
        *reinterpret_cast<ushort4*>(&WTz[(size_t)(c0 + oc) * R + r0 + tc4]) = u;
    }
}

// ---------------------------------------------------------------------------
// bf16 MFMA GEMM, 64x64 tile, BK=64, 256 thr (4 waves, 2x2 frags).
// DOUBLE-BUFFERED ping-pong: per iter, stage tile t+1 (A: global_load_lds,
// B: f32->regs) BEFORE the MFMAs of tile t; convert+ds_write B after the
// MFMAs; one __syncthreads per iter (its vmcnt/lgkm drain = buffer handoff).
// A: M x lda bf16 row-major (source-chunk skewed).
// B: K x ldb f32 row-major (native weights), transposed into Bs[n][k],
//    rows 72 ushorts (stride auto-de-conflicts), dword-skewed.
// ---------------------------------------------------------------------------
template <bool GATED>
__global__ __launch_bounds__(256) void mgemm_kernel(
    const ushort* __restrict__ A, const float* __restrict__ B,
    float* __restrict__ Cf, ushort* __restrict__ C16,
    const float* __restrict__ scale,
    int lda, int ldb, int ldc, int kc,
    int gate_off_cols, long b_z_stride, int c_z_col, int k_z_off,
    int scale_stride, int atomic_flag)
{
    __shared__ __align__(16) ushort As[2][64 * 64];
    __shared__ __align__(16) ushort Bs[2][64 * 72];
    __shared__ __align__(16) ushort Us[GATED ? 2 : 1][GATED ? 64 * 72 : 8];

    const int z = blockIdx.z;
    const int m0 = blockIdx.y * 64;
    const int n0 = blockIdx.x * 64;
    const int tid = threadIdx.x;
    const float* Bz = B + (size_t)z * b_z_stride;
    const int k0 = z * k_z_off;
    const int nt = kc >> 6;

    const int arow = tid >> 3;           // A staging row 0..31 (+32c)
    const int achk = tid & 7;            // A staging 16B slot
    const int bt = tid & 15;             // B staging n-group (n = 4*bt+i)
    const int bq = tid >> 4;             // B staging k-pair (+16p)

    const int lane = tid & 63;
    const int wave = tid >> 6;
    const int wr = (wave >> 1) * 32;
    const int wc = (wave & 1) * 32;
    const int lrow = lane & 15;
    const int lg = lane >> 4;

    f32x4 accg[2][2] = {};
    f32x4 accu[2][2] = {};
    float4 rb0[2], rb1[2], ru0[2], ru1[2];

    auto issueA = [&](int t, int buf) {
        const int kbase = k0 + t * 64;
        #pragma unroll
        for (int c = 0; c < 2; c++) {
            const int row = c * 32 + arow;
            const int cs = (achk + (row & 7)) & 7;
            gload16(A + (size_t)(m0 + row) * lda + kbase + cs * 8,
                    (char*)As[buf] + c * 4096 + tid * 16);
        }
    };
    auto loadB = [&](int t) {
        const int kbase = k0 + t * 64;
        #pragma unroll
        for (int p = 0; p < 2; p++) {
            const int kp = bq + p * 16;
            const long krow = (long)(kbase + kp * 2) * ldb + n0 + bt * 4;
            rb0[p] = *reinterpret_cast<const float4*>(Bz + krow);
            rb1[p] = *reinterpret_cast<const float4*>(Bz + krow + ldb);
            if constexpr (GATED) {
                ru0[p] = *reinterpret_cast<const float4*>(Bz + krow + gate_off_cols);
                ru1[p] = *reinterpret_cast<const float4*>(Bz + krow + ldb + gate_off_cols);
            }
        }
    };
    auto writeB = [&](int buf) {
        #pragma unroll
        for (int p = 0; p < 2; p++) {
            const int kp = bq + p * 16;
            #pragma unroll
            for (int i = 0; i < 4; i++) {
                const int n = bt * 4 + i;
                const int ld = (kp + 4 * ((n >> 2) & 7)) & 31;
                uint32_t pk = (uint32_t)f2bf(f4el(rb0[p], i)) |
                              ((uint32_t)f2bf(f4el(rb1[p], i)) << 16);
                *reinterpret_cast<uint32_t*>(&Bs[buf][n * 72 + ld * 2]) = pk;
                if constexpr (GATED) {
                    uint32_t pu = (uint32_t)f2bf(f4el(ru0[p], i)) |
                                  ((uint32_t)f2bf(f4el(ru1[p], i)) << 16);
                    *reinterpret_cast<uint32_t*>(&Us[buf][n * 72 + ld * 2]) = pu;
                }
            }
        }
    };

    // prologue: stage tile 0 into buffer 0
    issueA(0, 0);
    loadB(0);
    writeB(0);
    __syncthreads();

    for (int t = 0; t < nt; ++t) {
        const int cur = t & 1;
        const bool more = (t + 1 < nt);
        if (more) { issueA(t + 1, cur ^ 1); loadB(t + 1); }

        short8 af[2][2], bfr[2][2];
        #pragma unroll
        for (int mf = 0; mf < 2; mf++)
            #pragma unroll
            for (int kk = 0; kk < 2; kk++) {
                const int r = wr + mf * 16 + lrow;
                const int ch = kk * 4 + lg;
                const int sl = (ch - (r & 7)) & 7;
                af[mf][kk] = *reinterpret_cast<const short8*>(
                    (const char*)As[cur] + r * 128 + sl * 16);
            }
        #pragma unroll
        for (int nf = 0; nf < 2; nf++)
            #pragma unroll
            for (int kk = 0; kk < 2; kk++) {
                const int n = wc + nf * 16 + lrow;
                const int ldd = ((kk * 16 + lg * 4) + 4 * ((n >> 2) & 7)) & 31;
                bfr[nf][kk] = *reinterpret_cast<const short8*>(&Bs[cur][n * 72 + ldd * 2]);
            }
        #pragma unroll
        for (int mf = 0; mf < 2; mf++)
            #pragma unroll
            for (int nf = 0; nf < 2; nf++)
                #pragma unroll
                for (int kk = 0; kk < 2; kk++)
                    accg[mf][nf] = __builtin_amdgcn_mfma_f32_16x16x32_bf16(
                        af[mf][kk], bfr[nf][kk], accg[mf][nf], 0, 0, 0);
        if constexpr (GATED) {
            short8 uf[2][2];
            #pragma unroll
            for (int nf = 0; nf < 2; nf++)
                #pragma unroll
                for (int kk = 0; kk < 2; kk++) {
                    const int n = wc + nf * 16 + lrow;
                    const int ldd = ((kk * 16 + lg * 4) + 4 * ((n >> 2) & 7)) & 31;
                    uf[nf][kk] = *reinterpret_cast<const short8*>(&Us[cur][n * 72 + ldd * 2]);
                }
            #pragma unroll
            for (int mf = 0; mf < 2; mf++)
                #pragma unroll
                for (int nf = 0; nf < 2; nf++)
                    #pragma unroll
                    for (int kk = 0; kk < 2; kk++)
                        accu[mf][nf] = __builtin_amdgcn_mfma_f32_16x16x32_bf16(
                            af[mf][kk], uf[nf][kk], accu[mf][nf], 0, 0, 0);
        }

        if (more) writeB(cur ^ 1);   // vmcnt wait lands here, after the MFMAs
        __syncthreads();
    }

    // epilogue — C/D layout: col = lane&15, row = (lane>>4)*4 + j
    const int r4 = (lane >> 4) * 4;
    const int cl = lane & 15;
    const int ccol = z * c_z_col;
    #pragma unroll
    for (int mf = 0; mf < 2; mf++) {
        #pragma unroll
        for (int nf = 0; nf < 2; nf++) {
            #pragma unroll
            for (int j = 0; j < 4; j++) {
                const int row = m0 + wr + mf * 16 + r4 + j;
                const int col = ccol + n0 + wc + nf * 16 + cl;
                if constexpr (GATED) {
                    const float g = accg[mf][nf][j];
                    const float u = accu[mf][nf][j];
                    const float sv =
                        scale ? scale[(size_t)row * scale_stride + z] : 1.0f;
                    const float h = (g / (1.0f + __expf(-g))) * u * sv;
                    C16[(size_t)row * ldc + col] = f2bf(h);
                } else if (atomic_flag) {
                    atomicAdd(&Cf[(size_t)row * ldc + col], accg[mf][nf][j]);
                } else {
                    Cf[(size_t)row * ldc + col] = accg[mf][nf][j];
                }
            }
        }
    }
}

// ---------------------------------------------------------------------------
// RoPE + bf16 pack: Qb [16][T][64] (scaled by D^-0.5) and Kb [4][T][64]
// ---------------------------------------------------------------------------
__global__ __launch_bounds__(256) void rope_pack_kernel(
    const float* __restrict__ qkv, const int* __restrict__ positions,
    ushort* __restrict__ Qb, ushort* __restrict__ Kb)
{
    const int t = blockIdx.x;
    const float pos = (float)positions[t];
    for (int item = threadIdx.x; item < (kNQ + kNKV) * 32; item += 256) {
        const int head = item >> 5;
        const int i = item & 31;
        const float inv_freq = powf(10000.0f, -(float)i * (1.0f / 32.0f));
        const float f = pos * inv_freq;
        float sv, cv;
        sincosf(f, &sv, &cv);
        const size_t off = (size_t)t * kQKV + head * kD;
        const float x1 = qkv[off + i];
        const float x2 = qkv[off + 32 + i];
        const float r1 = x1 * cv - x2 * sv;
        const float r2 = x2 * cv + x1 * sv;
        if (head < kNQ) {
            ushort* q = Qb + ((size_t)head * kT + t) * kD;
            q[i] = f2bf(r1 * 0.125f);
            q[i + 32] = f2bf(r2 * 0.125f);
        } else {
            ushort* k = Kb + ((size_t)(head - kNQ) * kT + t) * kD;
            k[i] = f2bf(r1);
            k[i + 32] = f2bf(r2);
        }
    }
}

// ---------------------------------------------------------------------------
// Router: logits = h32 @ gate_w, softmax, top-2 -> combine (T x 8)
// ---------------------------------------------------------------------------
__global__ __launch_bounds__(64) void gate_topk_kernel(
    const float* __restrict__ h, const float* __restrict__ gate_w,
    float* __restrict__ combine)
{
    const int t = blockIdx.x;
    const int lane = threadIdx.x;
    float acc[kE] = {};
    for (int i = lane; i < kH; i += 64) {
        const float xv = h[(size_t)t * kH + i];
        const float* gw = gate_w + (size_t)i * kE;
        #pragma unroll
        for (int e = 0; e < kE; e++) acc[e] += xv * gw[e];
    }
    #pragma unroll
    for (int e = 0; e < kE; e++) {
        #pragma unroll
        for (int off = 32; off > 0; off >>= 1) acc[e] += __shfl_down(acc[e], off);
    }
    if (lane == 0) {
        float mx = acc[0];
        #pragma unroll
        for (int e = 1; e < kE; e++) mx = fmaxf(mx, acc[e]);
        float p[kE];
        float s = 0.0f;
        #pragma unroll
        for (int e = 0; e < kE; e++) { p[e] = expf(acc[e] - mx); s += p[e]; }
        const float invs = 1.0f / s;
        #pragma unroll
        for (int e = 0; e < kE; e++) p[e] *= invs;
        int i1 = 0;
        #pragma unroll
        for (int e = 1; e < kE; e++) if (p[e] > p[i1]) i1 = e;
        int i2 = (i1 == 0) ? 1 : 0;
        #pragma unroll
        for (int e = 0; e < kE; e++) if (e != i1 && p[e] > p[i2]) i2 = e;
        float outv[kE];
        #pragma unroll
        for (int e = 0; e < kE; e++) outv[e] = 0.0f;
        outv[i1] = p[i1];
        outv[i2] = p[i2];
        #pragma unroll
        for (int e = 0; e < kE; e++) combine[(size_t)t * kE + e] = outv[e];
    }
}

// ---------------------------------------------------------------------------
// MFMA flash attention (XOR-swizzled LDS, S^T=mfma(K,Q)) — unchanged
// ---------------------------------------------------------------------------
__global__ __launch_bounds__(256) void attn_mfma_kernel(
    const ushort* __restrict__ Qb, const ushort* __restrict__ Kb,
    const ushort* __restrict__ Vt, ushort* __restrict__ attn_o)
{
    __shared__ __align__(16) ushort Qs[64 * 64];
    __shared__ __align__(16) ushort Ks[64 * 64];
    __shared__ __align__(16) ushort Vs[64 * 64];
    __shared__ __align__(16) ushort Ps[64 * 64];
    const int tid = threadIdx.x;
    const int qb = blockIdx.x * 64;
    const int hq = blockIdx.y;
    const int kvh = hq >> 2;
    const int lane = tid & 63;
    const int wave = tid >> 6;
    const int lrow = lane & 15;
    const int g = lane >> 4;
    const int srow = tid >> 3;
    const int sx = tid & 7;
    const ushort* Qg = Qb + ((size_t)hq * kT + qb) * kD;
    const ushort* Kg = Kb + (size_t)kvh * kT * kD;
    const ushort* Vg = Vt + (size_t)kvh * kD * kT;
    const int xr = (lrow & 7) << 4;

    #pragma unroll
    for (int c = 0; c < 2; c++) {
        const int row = c * 32 + srow;
        gload16(Qg + (size_t)row * kD + ((sx ^ (row & 7)) * 8),
                (char*)Qs + c * 4096 + tid * 16);
    }
    __syncthreads();
    short8 qf[2];
    #pragma unroll
    for (int kk = 0; kk < 2; kk++)
        qf[kk] = *reinterpret_cast<const short8*>(
            (const char*)Qs + (16 * wave + lrow) * 128 + ((kk * 64 + g * 16) ^ xr));

    f32x4 oacc[4] = {};
    float mrow = -1e30f, lsum = 0.0f;

    for (int s0 = 0; s0 <= qb; s0 += 64) {
        __syncthreads();
        #pragma unroll
        for (int c = 0; c < 2; c++) {
            const int row = c * 32 + srow;
            gload16(Kg + (size_t)(s0 + row) * kD + ((sx ^ (row & 7)) * 8),
                    (char*)Ks + c * 4096 + tid * 16);
            gload16(Vg + (size_t)row * kT + s0 + ((sx ^ (row & 7)) * 8),
                    (char*)Vs + c * 4096 + tid * 16);
        }
        __syncthreads();

        f32x4 sacc[4] = {};
        #pragma unroll
        for (int nf = 0; nf < 4; nf++) {
            #pragma unroll
            for (int kk = 0; kk < 2; kk++) {
                short8 kf = *reinterpret_cast<const short8*>(
                    (const char*)Ks + (nf * 16 + lrow) * 128 + ((kk * 64 + g * 16) ^ xr));
                sacc[nf] = __builtin_amdgcn_mfma_f32_16x16x32_bf16(
                    kf, qf[kk], sacc[nf], 0, 0, 0);
            }
        }

        const bool diag = (s0 == qb);
        float pv[16];
        float mloc = -1e30f;
        #pragma unroll
        for (int nf = 0; nf < 4; nf++)
            #pragma unroll
            for (int j = 0; j < 4; j++) {
                float s = sacc[nf][j];
                if (diag && (nf * 16 + g * 4 + j > 16 * wave + lrow)) s = -1e30f;
                pv[nf * 4 + j] = s;
                mloc = fmaxf(mloc, s);
            }
        mloc = fmaxf(mloc, __shfl_xor(mloc, 16));
        mloc = fmaxf(mloc, __shfl_xor(mloc, 32));
        const float mnew = fmaxf(mrow, mloc);
        const float alpha = __expf(mrow - mnew);
        float psum = 0.0f;
        #pragma unroll
        for (int j = 0; j < 16; j++) { pv[j] = __expf(pv[j] - mnew); psum += pv[j]; }
        psum += __shfl_xor(psum, 16);
        psum += __shfl_xor(psum, 32);
        lsum = lsum * alpha + psum;
        mrow = mnew;

        const int prow = 16 * wave + lrow;
        #pragma unroll
        for (int nf = 0; nf < 4; nf++)
            #pragma unroll
            for (int jp = 0; jp < 2; jp++) {
                uint32_t pk = (uint32_t)f2bf(pv[nf * 4 + jp * 2]) |
                              ((uint32_t)f2bf(pv[nf * 4 + jp * 2 + 1]) << 16);
                *reinterpret_cast<uint32_t*>(
                    (char*)Ps + prow * 128 + ((nf * 32 + g * 8 + jp * 4) ^ xr)) = pk;
            }

        float aj[4];
        #pragma unroll
        for (int j = 0; j < 4; j++) aj[j] = __shfl(alpha, g * 4 + j);
        #pragma unroll
        for (int nf = 0; nf < 4; nf++)
            #pragma unroll
            for (int j = 0; j < 4; j++) oacc[nf][j] *= aj[j];

        short8 paf[2];
        #pragma unroll
        for (int kk = 0; kk < 2; kk++)
            paf[kk] = *reinterpret_cast<const short8*>(
                (const char*)Ps + prow * 128 + ((kk * 64 + g * 16) ^ xr));
        #pragma unroll
        for (int nf = 0; nf < 4; nf++)
            #pragma unroll
            for (int kk = 0; kk < 2; kk++) {
                short8 vf = *reinterpret_cast<const short8*>(
                    (const char*)Vs + (nf * 16 + lrow) * 128 + ((kk * 64 + g * 16) ^ xr));
                oacc[nf] = __builtin_amdgcn_mfma_f32_16x16x32_bf16(
                    paf[kk], vf, oacc[nf], 0, 0, 0);
            }
    }

    float lj[4];
    #pragma unroll
    for (int j = 0; j < 4; j++) lj[j] = 1.0f / __shfl(lsum, g * 4 + j);
    #pragma unroll
    for (int nf = 0; nf < 4; nf++)
        #pragma unroll
        for (int j = 0; j < 4; j++) {
            const int trow = qb + 16 * wave + g * 4 + j;
            attn_o[(size_t)trow * (kNQ * kD) + hq * kD + nf * 16 + lrow] =
                f2bf(oacc[nf][j] * lj[j]);
        }
}

__global__ __launch_bounds__(256) void final_out_kernel(
    const float* __restrict__ mlp, const float* __restrict__ shortcut,
    const float* __restrict__ r, float* __restrict__ out)
{
    const int i = blockIdx.x * 256 + threadIdx.x;
    float4 a = reinterpret_cast<const float4*>(mlp)[i];
    float4 b = reinterpret_cast<const float4*>(shortcut)[i];
    reinterpret_cast<float4*>(out)[i] =
        make_float4(a.x + b.x, a.y + b.y, a.z + b.z, a.w + b.w);
    reinterpret_cast<float4*>(out + (size_t)kT * kH)[i] =
        reinterpret_cast<const float4*>(r)[i];
}

}  // namespace

extern "C" void kernel_launch(void* const* d_in, const int* in_sizes, int n_in,
                              void* d_out, int out_size, void* d_ws, size_t ws_size,
                              hipStream_t stream) {
    (void)in_sizes; (void)n_in; (void)out_size; (void)ws_size;
    const float* hidden   = (const float*)d_in[0];
    const float* residual = (const float*)d_in[1];
    const int*   positions= (const int*)d_in[2];
    const float* ln0_w    = (const float*)d_in[3];
    const float* pa0_w    = (const float*)d_in[4];
    const float* ln1_w    = (const float*)d_in[5];
    const float* pa1_w    = (const float*)d_in[6];
    const float* qkv0_w   = (const float*)d_in[7];
    const float* o0_w     = (const float*)d_in[8];
    const float* qkv1_w   = (const float*)d_in[9];
    const float* o1_w     = (const float*)d_in[10];
    const float* gu0_w    = (const float*)d_in[11];
    const float* dn0_w    = (const float*)d_in[12];
    const float* gu1_w    = (const float*)d_in[13];
    const float* dn1_w    = (const float*)d_in[14];
    const float* gate_w   = (const float*)d_in[15];
    const float* w13      = (const float*)d_in[16];
    const float* w2       = (const float*)d_in[17];
    float* out_h = (float*)d_out;

    char* wsb = (char*)d_ws;
    float*  r_buf   = (float*)(wsb + (0ull  << 20));   // 4 MB
    float*  h32     = (float*)(wsb + (4ull  << 20));   // 4 MB
    float*  t0_buf  = (float*)(wsb + (8ull  << 20));   // 4 MB
    float*  qkv_buf = (float*)(wsb + (12ull << 20));   // 6 MB
    float*  sc_buf  = (float*)(wsb + (18ull << 20));   // 4 MB
    float*  cb_buf  = (float*)(wsb + (22ull << 20));   // 32 KB
    ushort* h16     = (ushort*)(wsb + (23ull << 20));  // 2 MB
    ushort* ao16    = (ushort*)(wsb + (25ull << 20));  // 2 MB
    ushort* he16    = (ushort*)(wsb + (27ull << 20));  // 8 MB
    ushort* Qb      = (ushort*)(wsb + (35ull << 20));  // 2 MB
    ushort* Kb      = (ushort*)(wsb + (37ull << 20));  // 0.5 MB
    ushort* VtG     = (ushort*)(wsb + (38ull << 20));  // 0.5 MB

    // C = A(bf16) @ B(f32 [K][N]) ; split-K via nz/kzoff + f32 atomics
    auto gemm_f32 = [&](const ushort* A, const float* B, float* C, int N,
                        int lda_, int ldb_, int ldc_, int nz, int kc, int kzoff,
                        int atomic) {
        mgemm_kernel<false><<<dim3(N / 64, kT / 64, nz), 256, 0, stream>>>(
            A, B, C, nullptr, nullptr, lda_, ldb_, ldc_, kc,
            0, 0, 0, kzoff, 0, atomic);
    };
    auto attention = [&](const float* qkv_w, const float* o_w) {
        gemm_f32(h16, qkv_w, qkv_buf, kQKV, kH, kQKV, kQKV, 1, kH, 0, 0);
        rope_pack_kernel<<<kT, 256, 0, stream>>>(qkv_buf, positions, Qb, Kb);
        transpose_bf16_kernel<<<dim3(1, kT / 64, kNKV), 256, 0, stream>>>(
            qkv_buf + (kNQ + kNKV) * kD, VtG, kT, kD, kQKV, kD, (long)kD * kT);
        attn_mfma_kernel<<<dim3(kT / 64, kNQ), 256, 0, stream>>>(Qb, Kb, VtG, ao16);
        hipMemsetAsync(t0_buf, 0, (size_t)kT * kH * 4, stream);
        gemm_f32(ao16, o_w, t0_buf, kH, kNQ * kD, kH, kH, 2, 512, 512, 1);
    };
    auto dense_mlp = [&](const float* gu_w, const float* dn_w) {
        mgemm_kernel<true><<<dim3(kIDense / 64, kT / 64, 1), 256, 0, stream>>>(
            h16, gu_w, nullptr, he16, nullptr, kH, 2 * kIDense, kIDense, kH,
            kIDense, 0, 0, 0, 0, 0);
        hipMemsetAsync(t0_buf, 0, (size_t)kT * kH * 4, stream);
        gemm_f32(he16, dn_w, t0_buf, kH, kIDense, kH, kH, 4, 1024, 1024, 1);
    };

    // h, r = add_rmsnorm(hidden, residual, ln0)
    add_rmsnorm_kernel<<<kT, 256, 0, stream>>>(hidden, residual, ln0_w, h32, h16, r_buf);
    // h = attention0(h) -> t0
    attention(qkv0_w, o0_w);
    // h, r = add_rmsnorm(t0, r, pa0)
    add_rmsnorm_kernel<<<kT, 256, 0, stream>>>(t0_buf, r_buf, pa0_w, h32, h16, r_buf);
    // shortcut = moe(h)
    gate_topk_kernel<<<kT, 64, 0, stream>>>(h32, gate_w, cb_buf);
    mgemm_kernel<true><<<dim3(kIMoe / 64, kT / 64, kE), 256, 0, stream>>>(
        h16, w13, nullptr, he16, cb_buf, kH, 2 * kIMoe, kIDense, kH,
        kIMoe, (long)kH * 2 * kIMoe, kIMoe, 0, kE, 0);
    hipMemsetAsync(sc_buf, 0, (size_t)kT * kH * 4, stream);
    gemm_f32(he16, w2, sc_buf, kH, kIDense, kH, kH, 4, 1024, 1024, 1);
    // h = dense_mlp0(h) -> t0
    dense_mlp(gu0_w, dn0_w);
    // h, r = add_rmsnorm(t0, r, ln1)
    add_rmsnorm_kernel<<<kT, 256, 0, stream>>>(t0_buf, r_buf, ln1_w, h32, h16, r_buf);
    // h = attention1(h) -> t0
    attention(qkv1_w, o1_w);
    // h, r = add_rmsnorm(t0, r, pa1)
    add_rmsnorm_kernel<<<kT, 256, 0, stream>>>(t0_buf, r_buf, pa1_w, h32, h16, r_buf);
    // h = dense_mlp1(h) -> t0
    dense_mlp(gu1_w, dn1_w);
    // out = (t0 + shortcut, r)
    final_out_kernel<<<(kT * kH / 4) / 256, 256, 0, stream>>>(t0_buf, sc_buf, r_buf, out_h);
}

// Round 7
// 392.050 us; speedup vs baseline: 1.0448x; 1.0448x over previous
//
#include <hip/hip_runtime.h>
#include <math.h>

namespace {

constexpr int kT = 1024;
constexpr int kH = 1024;
constexpr int kNQ = 16;
constexpr int kNKV = 4;
constexpr int kD = 64;
constexpr int kQKV = (kNQ + 2 * kNKV) * kD;   // 1536
constexpr int kIDense = 4096;
constexpr int kIMoe = 512;
constexpr int kE = 8;
constexpr float kEps = 1e-6f;

typedef __attribute__((ext_vector_type(8))) short short8;
typedef __attribute__((ext_vector_type(4))) float f32x4;

__device__ __forceinline__ ushort f2bf(float f) {
    union { float f; uint32_t u; } v; v.f = f;
    uint32_t r = (v.u + 0x7fffu + ((v.u >> 16) & 1u)) >> 16;
    return (ushort)r;
}
__device__ __forceinline__ float f4el(const float4& v, int i) {
    return (i == 0) ? v.x : (i == 1) ? v.y : (i == 2) ? v.z : v.w;
}
__device__ __forceinline__ void gload16(const void* g, void* l) {
    __builtin_amdgcn_global_load_lds(
        (const __attribute__((address_space(1))) void*)g,
        (__attribute__((address_space(3))) void*)l, 16, 0, 0);
}

// ---------------------------------------------------------------------------
// add + RMSNorm: r_out = x + res; h = rmsnorm(r_out)*w  -> h32 (f32) + h16 (bf16)
// ---------------------------------------------------------------------------
__global__ __launch_bounds__(256) void add_rmsnorm_kernel(
    const float* __restrict__ x, const float* __restrict__ res,
    const float* __restrict__ w, float* __restrict__ h32,
    ushort* __restrict__ h16, float* __restrict__ r_out)
{
    __shared__ float red[4];
    const int t = blockIdx.x;
    const int i = threadIdx.x;
    const size_t base = (size_t)t * kH;
    float4 a = reinterpret_cast<const float4*>(x + base)[i];
    float4 b = reinterpret_cast<const float4*>(res + base)[i];
    float4 s = make_float4(a.x + b.x, a.y + b.y, a.z + b.z, a.w + b.w);
    reinterpret_cast<float4*>(r_out + base)[i] = s;
    float ss = s.x * s.x + s.y * s.y + s.z * s.z + s.w * s.w;
    #pragma unroll
    for (int off = 32; off > 0; off >>= 1) ss += __shfl_down(ss, off);
    if ((i & 63) == 0) red[i >> 6] = ss;
    __syncthreads();
    const float tot = red[0] + red[1] + red[2] + red[3];
    const float inv = rsqrtf(tot * (1.0f / kH) + kEps);
    float4 wv = reinterpret_cast<const float4*>(w)[i];
    float4 o = make_float4(s.x * inv * wv.x, s.y * inv * wv.y,
                           s.z * inv * wv.z, s.w * inv * wv.w);
    reinterpret_cast<float4*>(h32 + base)[i] = o;
    ushort4 u;
    u.x = f2bf(o.x); u.y = f2bf(o.y); u.z = f2bf(o.z); u.w = f2bf(o.w);
    reinterpret_cast<ushort4*>(h16 + base)[i] = u;
}

// ---------------------------------------------------------------------------
// transpose + f32 -> bf16 (used only for attention V^T)
// ---------------------------------------------------------------------------
__global__ __launch_bounds__(256) void transpose_bf16_kernel(
    const float* __restrict__ W, ushort* __restrict__ WT,
    int R, int Cn, int ld_w, long w_z_stride, long wt_z_stride)
{
    __shared__ float tile[64][65];
    const int z = blockIdx.z;
    const float* Wz = W + (size_t)z * w_z_stride;
    ushort* WTz = WT + (size_t)z * wt_z_stride;
    const int r0 = blockIdx.y * 64;
    const int c0 = blockIdx.x * 64;
    const int tr = threadIdx.x >> 4;
    const int tc4 = (threadIdx.x & 15) * 4;
    #pragma unroll
    for (int p = 0; p < 4; p++) {
        float4 v = *reinterpret_cast<const float4*>(
            &Wz[(size_t)(r0 + p * 16 + tr) * ld_w + c0 + tc4]);
        tile[p * 16 + tr][tc4 + 0] = v.x;
        tile[p * 16 + tr][tc4 + 1] = v.y;
        tile[p * 16 + tr][tc4 + 2] = v.z;
        tile[p * 16 + tr][tc4 + 3] = v.w;
    }
    __syncthreads();
    #pragma unroll
    for (int p = 0; p < 4; p++) {
        const int oc = p * 16 + tr;
        ushort4 u;
        u.x = f2bf(tile[tc4 + 0][oc]);
        u.y = f2bf(tile[tc4 + 1][oc]);
        u.z = f2bf(tile[tc4 + 2][oc]);
        u.w = f2bf(tile[tc4 + 3][oc]);
        *reinterpret_cast<ushort4*>(&WTz[(size_t)(c0 + oc) * R + r0 + tc4]) = u;
    }
}

// ---------------------------------------------------------------------------
// bf16 MFMA GEMM, 64x64 tile, BK=64, 256 thr (4 waves, 2x2 frags).
// PIPELINED, LDS-lean: A double-buffered in LDS (gload16 issued early);
// B register-double-buffered (f32 loads for t+1 issued before MFMAs of t,
// converted+ds_written after barrier into the SINGLE Bs/Us buffer).
//   loop: issueA(t+1,alt) ; loadB(t+1)->regs ; ds_read frags(t) ; MFMA(t)
//         ; barrier ; writeB(t+1) ; barrier
// A: M x lda bf16 row-major (source-chunk skewed).
// B: K x ldb f32 row-major (native weights) -> Bs[n][k] rows 72 ushorts,
//    dword-skewed (kdw + 4*((n>>2)&7)) & 31.
// ---------------------------------------------------------------------------
template <bool GATED>
__global__ __launch_bounds__(256) void mgemm_kernel(
    const ushort* __restrict__ A, const float* __restrict__ B,
    float* __restrict__ Cf, ushort* __restrict__ C16,
    const float* __restrict__ scale,
    int lda, int ldb, int ldc, int kc,
    int gate_off_cols, long b_z_stride, int c_z_col, int k_z_off,
    int scale_stride, int atomic_flag)
{
    __shared__ __align__(16) ushort As[2][64 * 64];
    __shared__ __align__(16) ushort Bs[64 * 72];
    __shared__ __align__(16) ushort Us[GATED ? 64 * 72 : 8];

    const int z = blockIdx.z;
    const int m0 = blockIdx.y * 64;
    const int n0 = blockIdx.x * 64;
    const int tid = threadIdx.x;
    const float* Bz = B + (size_t)z * b_z_stride;
    const int k0 = z * k_z_off;
    const int nt = kc >> 6;

    const int arow = tid >> 3;           // A staging row 0..31 (+32c)
    const int achk = tid & 7;            // A staging 16B slot
    const int bt = tid & 15;             // B staging n-group (n = 4*bt+i)
    const int bq = tid >> 4;             // B staging k-pair (+16p)

    const int lane = tid & 63;
    const int wave = tid >> 6;
    const int wr = (wave >> 1) * 32;
    const int wc = (wave & 1) * 32;
    const int lrow = lane & 15;
    const int lg = lane >> 4;

    f32x4 accg[2][2] = {};
    f32x4 accu[2][2] = {};
    float4 rb0[2], rb1[2], ru0[2], ru1[2];

    auto issueA = [&](int t, int buf) {
        const int kbase = k0 + t * 64;
        #pragma unroll
        for (int c = 0; c < 2; c++) {
            const int row = c * 32 + arow;
            const int cs = (achk + (row & 7)) & 7;
            gload16(A + (size_t)(m0 + row) * lda + kbase + cs * 8,
                    (char*)As[buf] + c * 4096 + tid * 16);
        }
    };
    auto loadB = [&](int t) {
        const int kbase = k0 + t * 64;
        #pragma unroll
        for (int p = 0; p < 2; p++) {
            const int kp = bq + p * 16;
            const long krow = (long)(kbase + kp * 2) * ldb + n0 + bt * 4;
            rb0[p] = *reinterpret_cast<const float4*>(Bz + krow);
            rb1[p] = *reinterpret_cast<const float4*>(Bz + krow + ldb);
            if constexpr (GATED) {
                ru0[p] = *reinterpret_cast<const float4*>(Bz + krow + gate_off_cols);
                ru1[p] = *reinterpret_cast<const float4*>(Bz + krow + ldb + gate_off_cols);
            }
        }
    };
    auto writeB = [&]() {
        #pragma unroll
        for (int p = 0; p < 2; p++) {
            const int kp = bq + p * 16;
            #pragma unroll
            for (int i = 0; i < 4; i++) {
                const int n = bt * 4 + i;
                const int ld = (kp + 4 * ((n >> 2) & 7)) & 31;
                uint32_t pk = (uint32_t)f2bf(f4el(rb0[p], i)) |
                              ((uint32_t)f2bf(f4el(rb1[p], i)) << 16);
                *reinterpret_cast<uint32_t*>(&Bs[n * 72 + ld * 2]) = pk;
                if constexpr (GATED) {
                    uint32_t pu = (uint32_t)f2bf(f4el(ru0[p], i)) |
                                  ((uint32_t)f2bf(f4el(ru1[p], i)) << 16);
                    *reinterpret_cast<uint32_t*>(&Us[n * 72 + ld * 2]) = pu;
                }
            }
        }
    };

    // prologue: stage tile 0
    issueA(0, 0);
    loadB(0);
    writeB();
    __syncthreads();   // drains gload16(A0) + publishes B0

    for (int t = 0; t < nt; ++t) {
        const int cur = t & 1;
        const bool more = (t + 1 < nt);
        if (more) {
            issueA(t + 1, cur ^ 1);    // gload16 -> other A buffer, in flight
            loadB(t + 1);              // f32 B loads -> regs, in flight
        }

        short8 af[2][2], bfr[2][2];
        #pragma unroll
        for (int mf = 0; mf < 2; mf++)
            #pragma unroll
            for (int kk = 0; kk < 2; kk++) {
                const int r = wr + mf * 16 + lrow;
                const int ch = kk * 4 + lg;
                const int sl = (ch - (r & 7)) & 7;
                af[mf][kk] = *reinterpret_cast<const short8*>(
                    (const char*)As[cur] + r * 128 + sl * 16);
            }
        #pragma unroll
        for (int nf = 0; nf < 2; nf++)
            #pragma unroll
            for (int kk = 0; kk < 2; kk++) {
                const int n = wc + nf * 16 + lrow;
                const int ldd = ((kk * 16 + lg * 4) + 4 * ((n >> 2) & 7)) & 31;
                bfr[nf][kk] = *reinterpret_cast<const short8*>(&Bs[n * 72 + ldd * 2]);
            }
        #pragma unroll
        for (int mf = 0; mf < 2; mf++)
            #pragma unroll
            for (int nf = 0; nf < 2; nf++)
                #pragma unroll
                for (int kk = 0; kk < 2; kk++)
                    accg[mf][nf] = __builtin_amdgcn_mfma_f32_16x16x32_bf16(
                        af[mf][kk], bfr[nf][kk], accg[mf][nf], 0, 0, 0);
        if constexpr (GATED) {
            short8 uf[2][2];
            #pragma unroll
            for (int nf = 0; nf < 2; nf++)
                #pragma unroll
                for (int kk = 0; kk < 2; kk++) {
                    const int n = wc + nf * 16 + lrow;
                    const int ldd = ((kk * 16 + lg * 4) + 4 * ((n >> 2) & 7)) & 31;
                    uf[nf][kk] = *reinterpret_cast<const short8*>(&Us[n * 72 + ldd * 2]);
                }
            #pragma unroll
            for (int mf = 0; mf < 2; mf++)
                #pragma unroll
                for (int nf = 0; nf < 2; nf++)
                    #pragma unroll
                    for (int kk = 0; kk < 2; kk++)
                        accu[mf][nf] = __builtin_amdgcn_mfma_f32_16x16x32_bf16(
                            af[mf][kk], uf[nf][kk], accu[mf][nf], 0, 0, 0);
        }

        __syncthreads();               // all waves done reading Bs/Us (+As[cur])
        if (more) {
            writeB();                  // vmcnt wait for B(t+1) lands HERE
            __syncthreads();           // publish B(t+1); drains gload16 A(t+1)
        }
    }

    // epilogue — C/D layout: col = lane&15, row = (lane>>4)*4 + j
    const int r4 = (lane >> 4) * 4;
    const int cl = lane & 15;
    const int ccol = z * c_z_col;
    #pragma unroll
    for (int mf = 0; mf < 2; mf++) {
        #pragma unroll
        for (int nf = 0; nf < 2; nf++) {
            #pragma unroll
            for (int j = 0; j < 4; j++) {
                const int row = m0 + wr + mf * 16 + r4 + j;
                const int col = ccol + n0 + wc + nf * 16 + cl;
                if constexpr (GATED) {
                    const float g = accg[mf][nf][j];
                    const float u = accu[mf][nf][j];
                    const float sv =
                        scale ? scale[(size_t)row * scale_stride + z] : 1.0f;
                    const float h = (g / (1.0f + __expf(-g))) * u * sv;
                    C16[(size_t)row * ldc + col] = f2bf(h);
                } else if (atomic_flag) {
                    atomicAdd(&Cf[(size_t)row * ldc + col], accg[mf][nf][j]);
                } else {
                    Cf[(size_t)row * ldc + col] = accg[mf][nf][j];
                }
            }
        }
    }
}

// ---------------------------------------------------------------------------
// RoPE + bf16 pack: Qb [16][T][64] (scaled by D^-0.5) and Kb [4][T][64]
// ---------------------------------------------------------------------------
__global__ __launch_bounds__(256) void rope_pack_kernel(
    const float* __restrict__ qkv, const int* __restrict__ positions,
    ushort* __restrict__ Qb, ushort* __restrict__ Kb)
{
    const int t = blockIdx.x;
    const float pos = (float)positions[t];
    for (int item = threadIdx.x; item < (kNQ + kNKV) * 32; item += 256) {
        const int head = item >> 5;
        const int i = item & 31;
        const float inv_freq = powf(10000.0f, -(float)i * (1.0f / 32.0f));
        const float f = pos * inv_freq;
        float sv, cv;
        sincosf(f, &sv, &cv);
        const size_t off = (size_t)t * kQKV + head * kD;
        const float x1 = qkv[off + i];
        const float x2 = qkv[off + 32 + i];
        const float r1 = x1 * cv - x2 * sv;
        const float r2 = x2 * cv + x1 * sv;
        if (head < kNQ) {
            ushort* q = Qb + ((size_t)head * kT + t) * kD;
            q[i] = f2bf(r1 * 0.125f);
            q[i + 32] = f2bf(r2 * 0.125f);
        } else {
            ushort* k = Kb + ((size_t)(head - kNQ) * kT + t) * kD;
            k[i] = f2bf(r1);
            k[i + 32] = f2bf(r2);
        }
    }
}

// ---------------------------------------------------------------------------
// Router: logits = h32 @ gate_w, softmax, top-2 -> combine (T x 8)
// ---------------------------------------------------------------------------
__global__ __launch_bounds__(64) void gate_topk_kernel(
    const float* __restrict__ h, const float* __restrict__ gate_w,
    float* __restrict__ combine)
{
    const int t = blockIdx.x;
    const int lane = threadIdx.x;
    float acc[kE] = {};
    for (int i = lane; i < kH; i += 64) {
        const float xv = h[(size_t)t * kH + i];
        const float* gw = gate_w + (size_t)i * kE;
        #pragma unroll
        for (int e = 0; e < kE; e++) acc[e] += xv * gw[e];
    }
    #pragma unroll
    for (int e = 0; e < kE; e++) {
        #pragma unroll
        for (int off = 32; off > 0; off >>= 1) acc[e] += __shfl_down(acc[e], off);
    }
    if (lane == 0) {
        float mx = acc[0];
        #pragma unroll
        for (int e = 1; e < kE; e++) mx = fmaxf(mx, acc[e]);
        float p[kE];
        float s = 0.0f;
        #pragma unroll
        for (int e = 0; e < kE; e++) { p[e] = expf(acc[e] - mx); s += p[e]; }
        const float invs = 1.0f / s;
        #pragma unroll
        for (int e = 0; e < kE; e++) p[e] *= invs;
        int i1 = 0;
        #pragma unroll
        for (int e = 1; e < kE; e++) if (p[e] > p[i1]) i1 = e;
        int i2 = (i1 == 0) ? 1 : 0;
        #pragma unroll
        for (int e = 0; e < kE; e++) if (e != i1 && p[e] > p[i2]) i2 = e;
        float outv[kE];
        #pragma unroll
        for (int e = 0; e < kE; e++) outv[e] = 0.0f;
        outv[i1] = p[i1];
        outv[i2] = p[i2];
        #pragma unroll
        for (int e = 0; e < kE; e++) combine[(size_t)t * kE + e] = outv[e];
    }
}

// ---------------------------------------------------------------------------
// MFMA flash attention (XOR-swizzled LDS, S^T=mfma(K,Q)) — unchanged
// ---------------------------------------------------------------------------
__global__ __launch_bounds__(256) void attn_mfma_kernel(
    const ushort* __restrict__ Qb, const ushort* __restrict__ Kb,
    const ushort* __restrict__ Vt, ushort* __restrict__ attn_o)
{
    __shared__ __align__(16) ushort Qs[64 * 64];
    __shared__ __align__(16) ushort Ks[64 * 64];
    __shared__ __align__(16) ushort Vs[64 * 64];
    __shared__ __align__(16) ushort Ps[64 * 64];
    const int tid = threadIdx.x;
    const int qb = blockIdx.x * 64;
    const int hq = blockIdx.y;
    const int kvh = hq >> 2;
    const int lane = tid & 63;
    const int wave = tid >> 6;
    const int lrow = lane & 15;
    const int g = lane >> 4;
    const int srow = tid >> 3;
    const int sx = tid & 7;
    const ushort* Qg = Qb + ((size_t)hq * kT + qb) * kD;
    const ushort* Kg = Kb + (size_t)kvh * kT * kD;
    const ushort* Vg = Vt + (size_t)kvh * kD * kT;
    const int xr = (lrow & 7) << 4;

    #pragma unroll
    for (int c = 0; c < 2; c++) {
        const int row = c * 32 + srow;
        gload16(Qg + (size_t)row * kD + ((sx ^ (row & 7)) * 8),
                (char*)Qs + c * 4096 + tid * 16);
    }
    __syncthreads();
    short8 qf[2];
    #pragma unroll
    for (int kk = 0; kk < 2; kk++)
        qf[kk] = *reinterpret_cast<const short8*>(
            (const char*)Qs + (16 * wave + lrow) * 128 + ((kk * 64 + g * 16) ^ xr));

    f32x4 oacc[4] = {};
    float mrow = -1e30f, lsum = 0.0f;

    for (int s0 = 0; s0 <= qb; s0 += 64) {
        __syncthreads();
        #pragma unroll
        for (int c = 0; c < 2; c++) {
            const int row = c * 32 + srow;
            gload16(Kg + (size_t)(s0 + row) * kD + ((sx ^ (row & 7)) * 8),
                    (char*)Ks + c * 4096 + tid * 16);
            gload16(Vg + (size_t)row * kT + s0 + ((sx ^ (row & 7)) * 8),
                    (char*)Vs + c * 4096 + tid * 16);
        }
        __syncthreads();

        f32x4 sacc[4] = {};
        #pragma unroll
        for (int nf = 0; nf < 4; nf++) {
            #pragma unroll
            for (int kk = 0; kk < 2; kk++) {
                short8 kf = *reinterpret_cast<const short8*>(
                    (const char*)Ks + (nf * 16 + lrow) * 128 + ((kk * 64 + g * 16) ^ xr));
                sacc[nf] = __builtin_amdgcn_mfma_f32_16x16x32_bf16(
                    kf, qf[kk], sacc[nf], 0, 0, 0);
            }
        }

        const bool diag = (s0 == qb);
        float pv[16];
        float mloc = -1e30f;
        #pragma unroll
        for (int nf = 0; nf < 4; nf++)
            #pragma unroll
            for (int j = 0; j < 4; j++) {
                float s = sacc[nf][j];
                if (diag && (nf * 16 + g * 4 + j > 16 * wave + lrow)) s = -1e30f;
                pv[nf * 4 + j] = s;
                mloc = fmaxf(mloc, s);
            }
        mloc = fmaxf(mloc, __shfl_xor(mloc, 16));
        mloc = fmaxf(mloc, __shfl_xor(mloc, 32));
        const float mnew = fmaxf(mrow, mloc);
        const float alpha = __expf(mrow - mnew);
        float psum = 0.0f;
        #pragma unroll
        for (int j = 0; j < 16; j++) { pv[j] = __expf(pv[j] - mnew); psum += pv[j]; }
        psum += __shfl_xor(psum, 16);
        psum += __shfl_xor(psum, 32);
        lsum = lsum * alpha + psum;
        mrow = mnew;

        const int prow = 16 * wave + lrow;
        #pragma unroll
        for (int nf = 0; nf < 4; nf++)
            #pragma unroll
            for (int jp = 0; jp < 2; jp++) {
                uint32_t pk = (uint32_t)f2bf(pv[nf * 4 + jp * 2]) |
                              ((uint32_t)f2bf(pv[nf * 4 + jp * 2 + 1]) << 16);
                *reinterpret_cast<uint32_t*>(
                    (char*)Ps + prow * 128 + ((nf * 32 + g * 8 + jp * 4) ^ xr)) = pk;
            }

        float aj[4];
        #pragma unroll
        for (int j = 0; j < 4; j++) aj[j] = __shfl(alpha, g * 4 + j);
        #pragma unroll
        for (int nf = 0; nf < 4; nf++)
            #pragma unroll
            for (int j = 0; j < 4; j++) oacc[nf][j] *= aj[j];

        short8 paf[2];
        #pragma unroll
        for (int kk = 0; kk < 2; kk++)
            paf[kk] = *reinterpret_cast<const short8*>(
                (const char*)Ps + prow * 128 + ((kk * 64 + g * 16) ^ xr));
        #pragma unroll
        for (int nf = 0; nf < 4; nf++)
            #pragma unroll
            for (int kk = 0; kk < 2; kk++) {
                short8 vf = *reinterpret_cast<const short8*>(
                    (const char*)Vs + (nf * 16 + lrow) * 128 + ((kk * 64 + g * 16) ^ xr));
                oacc[nf] = __builtin_amdgcn_mfma_f32_16x16x32_bf16(
                    paf[kk], vf, oacc[nf], 0, 0, 0);
            }
    }

    float lj[4];
    #pragma unroll
    for (int j = 0; j < 4; j++) lj[j] = 1.0f / __shfl(lsum, g * 4 + j);
    #pragma unroll
    for (int nf = 0; nf < 4; nf++)
        #pragma unroll
        for (int j = 0; j < 4; j++) {
            const int trow = qb + 16 * wave + g * 4 + j;
            attn_o[(size_t)trow * (kNQ * kD) + hq * kD + nf * 16 + lrow] =
                f2bf(oacc[nf][j] * lj[j]);
        }
}

__global__ __launch_bounds__(256) void final_out_kernel(
    const float* __restrict__ mlp, const float* __restrict__ shortcut,
    const float* __restrict__ r, float* __restrict__ out)
{
    const int i = blockIdx.x * 256 + threadIdx.x;
    float4 a = reinterpret_cast<const float4*>(mlp)[i];
    float4 b = reinterpret_cast<const float4*>(shortcut)[i];
    reinterpret_cast<float4*>(out)[i] =
        make_float4(a.x + b.x, a.y + b.y, a.z + b.z, a.w + b.w);
    reinterpret_cast<float4*>(out + (size_t)kT * kH)[i] =
        reinterpret_cast<const float4*>(r)[i];
}

}  // namespace

extern "C" void kernel_launch(void* const* d_in, const int* in_sizes, int n_in,
                              void* d_out, int out_size, void* d_ws, size_t ws_size,
                              hipStream_t stream) {
    (void)in_sizes; (void)n_in; (void)out_size; (void)ws_size;
    const float* hidden   = (const float*)d_in[0];
    const float* residual = (const float*)d_in[1];
    const int*   positions= (const int*)d_in[2];
    const float* ln0_w    = (const float*)d_in[3];
    const float* pa0_w    = (const float*)d_in[4];
    const float* ln1_w    = (const float*)d_in[5];
    const float* pa1_w    = (const float*)d_in[6];
    const float* qkv0_w   = (const float*)d_in[7];
    const float* o0_w     = (const float*)d_in[8];
    const float* qkv1_w   = (const float*)d_in[9];
    const float* o1_w     = (const float*)d_in[10];
    const float* gu0_w    = (const float*)d_in[11];
    const float* dn0_w    = (const float*)d_in[12];
    const float* gu1_w    = (const float*)d_in[13];
    const float* dn1_w    = (const float*)d_in[14];
    const float* gate_w   = (const float*)d_in[15];
    const float* w13      = (const float*)d_in[16];
    const float* w2       = (const float*)d_in[17];
    float* out_h = (float*)d_out;

    char* wsb = (char*)d_ws;
    float*  r_buf   = (float*)(wsb + (0ull  << 20));   // 4 MB
    float*  h32     = (float*)(wsb + (4ull  << 20));   // 4 MB
    float*  t0_buf  = (float*)(wsb + (8ull  << 20));   // 4 MB
    float*  qkv_buf = (float*)(wsb + (12ull << 20));   // 6 MB
    float*  sc_buf  = (float*)(wsb + (18ull << 20));   // 4 MB
    float*  cb_buf  = (float*)(wsb + (22ull << 20));   // 32 KB
    ushort* h16     = (ushort*)(wsb + (23ull << 20));  // 2 MB
    ushort* ao16    = (ushort*)(wsb + (25ull << 20));  // 2 MB
    ushort* he16    = (ushort*)(wsb + (27ull << 20));  // 8 MB
    ushort* Qb      = (ushort*)(wsb + (35ull << 20));  // 2 MB
    ushort* Kb      = (ushort*)(wsb + (37ull << 20));  // 0.5 MB
    ushort* VtG     = (ushort*)(wsb + (38ull << 20));  // 0.5 MB

    // C = A(bf16) @ B(f32 [K][N]) ; split-K via nz/kzoff + f32 atomics
    auto gemm_f32 = [&](const ushort* A, const float* B, float* C, int N,
                        int lda_, int ldb_, int ldc_, int nz, int kc, int kzoff,
                        int atomic) {
        mgemm_kernel<false><<<dim3(N / 64, kT / 64, nz), 256, 0, stream>>>(
            A, B, C, nullptr, nullptr, lda_, ldb_, ldc_, kc,
            0, 0, 0, kzoff, 0, atomic);
    };
    auto attention = [&](const float* qkv_w, const float* o_w) {
        gemm_f32(h16, qkv_w, qkv_buf, kQKV, kH, kQKV, kQKV, 1, kH, 0, 0);
        rope_pack_kernel<<<kT, 256, 0, stream>>>(qkv_buf, positions, Qb, Kb);
        transpose_bf16_kernel<<<dim3(1, kT / 64, kNKV), 256, 0, stream>>>(
            qkv_buf + (kNQ + kNKV) * kD, VtG, kT, kD, kQKV, kD, (long)kD * kT);
        attn_mfma_kernel<<<dim3(kT / 64, kNQ), 256, 0, stream>>>(Qb, Kb, VtG, ao16);
        hipMemsetAsync(t0_buf, 0, (size_t)kT * kH * 4, stream);
        gemm_f32(ao16, o_w, t0_buf, kH, kNQ * kD, kH, kH, 2, 512, 512, 1);
    };
    auto dense_mlp = [&](const float* gu_w, const float* dn_w) {
        mgemm_kernel<true><<<dim3(kIDense / 64, kT / 64, 1), 256, 0, stream>>>(
            h16, gu_w, nullptr, he16, nullptr, kH, 2 * kIDense, kIDense, kH,
            kIDense, 0, 0, 0, 0, 0);
        hipMemsetAsync(t0_buf, 0, (size_t)kT * kH * 4, stream);
        gemm_f32(he16, dn_w, t0_buf, kH, kIDense, kH, kH, 4, 1024, 1024, 1);
    };

    // h, r = add_rmsnorm(hidden, residual, ln0)
    add_rmsnorm_kernel<<<kT, 256, 0, stream>>>(hidden, residual, ln0_w, h32, h16, r_buf);
    // h = attention0(h) -> t0
    attention(qkv0_w, o0_w);
    // h, r = add_rmsnorm(t0, r, pa0)
    add_rmsnorm_kernel<<<kT, 256, 0, stream>>>(t0_buf, r_buf, pa0_w, h32, h16, r_buf);
    // shortcut = moe(h)
    gate_topk_kernel<<<kT, 64, 0, stream>>>(h32, gate_w, cb_buf);
    mgemm_kernel<true><<<dim3(kIMoe / 64, kT / 64, kE), 256, 0, stream>>>(
        h16, w13, nullptr, he16, cb_buf, kH, 2 * kIMoe, kIDense, kH,
        kIMoe, (long)kH * 2 * kIMoe, kIMoe, 0, kE, 0);
    hipMemsetAsync(sc_buf, 0, (size_t)kT * kH * 4, stream);
    gemm_f32(he16, w2, sc_buf, kH, kIDense, kH, kH, 4, 1024, 1024, 1);
    // h = dense_mlp0(h) -> t0
    dense_mlp(gu0_w, dn0_w);
    // h, r = add_rmsnorm(t0, r, ln1)
    add_rmsnorm_kernel<<<kT, 256, 0, stream>>>(t0_buf, r_buf, ln1_w, h32, h16, r_buf);
    // h = attention1(h) -> t0
    attention(qkv1_w, o1_w);
    // h, r = add_rmsnorm(t0, r, pa1)
    add_rmsnorm_kernel<<<kT, 256, 0, stream>>>(t0_buf, r_buf, pa1_w, h32, h16, r_buf);
    // h = dense_mlp1(h) -> t0
    dense_mlp(gu1_w, dn1_w);
    // out = (t0 + shortcut, r)
    final_out_kernel<<<(kT * kH / 4) / 256, 256, 0, stream>>>(t0_buf, sc_buf, r_buf, out_h);
}

// Round 8
// 375.017 us; speedup vs baseline: 1.0923x; 1.0454x over previous
//
#include <hip/hip_runtime.h>
#include <math.h>

namespace {

constexpr int kT = 1024;
constexpr int kH = 1024;
constexpr int kNQ = 16;
constexpr int kNKV = 4;
constexpr int kD = 64;
constexpr int kQKV = (kNQ + 2 * kNKV) * kD;   // 1536
constexpr int kIDense = 4096;
constexpr int kIMoe = 512;
constexpr int kE = 8;
constexpr float kEps = 1e-6f;

typedef __attribute__((ext_vector_type(8))) short short8;
typedef __attribute__((ext_vector_type(4))) float f32x4;

__device__ __forceinline__ ushort f2bf(float f) {
    union { float f; uint32_t u; } v; v.f = f;
    uint32_t r = (v.u + 0x7fffu + ((v.u >> 16) & 1u)) >> 16;
    return (ushort)r;
}
__device__ __forceinline__ void gload16(const void* g, void* l) {
    __builtin_amdgcn_global_load_lds(
        (const __attribute__((address_space(1))) void*)g,
        (__attribute__((address_space(3))) void*)l, 16, 0, 0);
}

// ---------------------------------------------------------------------------
// add + RMSNorm: r_out = x + res; h = rmsnorm(r_out)*w  -> h32 (f32) + h16 (bf16)
// ---------------------------------------------------------------------------
__global__ __launch_bounds__(256) void add_rmsnorm_kernel(
    const float* __restrict__ x, const float* __restrict__ res,
    const float* __restrict__ w, float* __restrict__ h32,
    ushort* __restrict__ h16, float* __restrict__ r_out)
{
    __shared__ float red[4];
    const int t = blockIdx.x;
    const int i = threadIdx.x;
    const size_t base = (size_t)t * kH;
    float4 a = reinterpret_cast<const float4*>(x + base)[i];
    float4 b = reinterpret_cast<const float4*>(res + base)[i];
    float4 s = make_float4(a.x + b.x, a.y + b.y, a.z + b.z, a.w + b.w);
    reinterpret_cast<float4*>(r_out + base)[i] = s;
    float ss = s.x * s.x + s.y * s.y + s.z * s.z + s.w * s.w;
    #pragma unroll
    for (int off = 32; off > 0; off >>= 1) ss += __shfl_down(ss, off);
    if ((i & 63) == 0) red[i >> 6] = ss;
    __syncthreads();
    const float tot = red[0] + red[1] + red[2] + red[3];
    const float inv = rsqrtf(tot * (1.0f / kH) + kEps);
    float4 wv = reinterpret_cast<const float4*>(w)[i];
    float4 o = make_float4(s.x * inv * wv.x, s.y * inv * wv.y,
                           s.z * inv * wv.z, s.w * inv * wv.w);
    reinterpret_cast<float4*>(h32 + base)[i] = o;
    ushort4 u;
    u.x = f2bf(o.x); u.y = f2bf(o.y); u.z = f2bf(o.z); u.w = f2bf(o.w);
    reinterpret_cast<ushort4*>(h16 + base)[i] = u;
}

// ---------------------------------------------------------------------------
// Fast transpose + f32 -> bf16: W (R x Cn f32, row stride ld_w) -> WT (Cn x R).
// 64x64 tiles, pad-65 LDS (2-way reads), 16-elem bf16 pack, short8 stores.
// ---------------------------------------------------------------------------
__global__ __launch_bounds__(256) void transpose_bf16_kernel(
    const float* __restrict__ W, ushort* __restrict__ WT,
    int R, int Cn, int ld_w, long w_z_stride, long wt_z_stride)
{
    __shared__ float tile[64 * 65];
    const int z = blockIdx.z;
    const float* Wz = W + (size_t)z * w_z_stride;
    ushort* WTz = WT + (size_t)z * wt_z_stride;
    const int r0 = blockIdx.y * 64;
    const int c0 = blockIdx.x * 64;
    const int tid = threadIdx.x;
    const int lr = tid >> 4;
    const int lc = (tid & 15) * 4;
    #pragma unroll
    for (int p = 0; p < 4; p++) {
        const int row = p * 16 + lr;
        float4 v = *reinterpret_cast<const float4*>(
            &Wz[(size_t)(r0 + row) * ld_w + c0 + lc]);
        tile[row * 65 + lc + 0] = v.x;
        tile[row * 65 + lc + 1] = v.y;
        tile[row * 65 + lc + 2] = v.z;
        tile[row * 65 + lc + 3] = v.w;
    }
    __syncthreads();
    const int ocl = tid >> 2;           // out row (= in col) 0..63
    const int q = tid & 3;              // 16-element chunk along in-rows
    ushort u[16];
    #pragma unroll
    for (int e = 0; e < 16; e++)
        u[e] = f2bf(tile[(q * 16 + e) * 65 + ocl]);
    ushort* dst = &WTz[(size_t)(c0 + ocl) * R + r0 + q * 16];
    *reinterpret_cast<short8*>(dst) = *reinterpret_cast<short8*>(&u[0]);
    *reinterpret_cast<short8*>(dst + 8) = *reinterpret_cast<short8*>(&u[8]);
}

// ---------------------------------------------------------------------------
// bf16 MFMA GEMM, 64x64 tile, BK=64, 256 thr (4 waves, 2x2 frags).
// BOTH operands bf16, staged via global_load_lds with source-chunk skew
// (LDS linear; global chunk cs=(achk+row&7)&7; frag read slot (ch-row&7)&7
//  -> 2-way conflict-free). Single-buffer, stage->sync->MFMA->sync.
// A: M x lda bf16 row-major. B: N x ldb bf16 row-major (weight^T).
// GATED: also stages rows [gate_off_rows+n]; out bf16 = silu(g)*u*scale.
// ---------------------------------------------------------------------------
template <bool GATED>
__global__ __launch_bounds__(256) void mgemm_kernel(
    const ushort* __restrict__ A, const ushort* __restrict__ B,
    float* __restrict__ Cf, ushort* __restrict__ C16,
    const float* __restrict__ scale,
    int lda, int ldb, int ldc, int kc,
    int gate_off_rows, long b_z_stride, int c_z_col, int k_z_off,
    int scale_stride, int atomic_flag)
{
    __shared__ __align__(16) ushort As[64 * 64];
    __shared__ __align__(16) ushort Bs[64 * 64];
    __shared__ __align__(16) ushort Us[GATED ? 64 * 64 : 8];

    const int z = blockIdx.z;
    const int m0 = blockIdx.y * 64;
    const int n0 = blockIdx.x * 64;
    const int tid = threadIdx.x;
    const ushort* Bz = B + (size_t)z * b_z_stride;
    const int k0 = z * k_z_off;

    const int arow = tid >> 3;           // staging row 0..31 (+32c)
    const int achk = tid & 7;            // staging 16B slot

    const int lane = tid & 63;
    const int wave = tid >> 6;
    const int wr = (wave >> 1) * 32;
    const int wc = (wave & 1) * 32;
    const int lrow = lane & 15;
    const int lg = lane >> 4;

    f32x4 accg[2][2] = {};
    f32x4 accu[2][2] = {};

    for (int kk0 = 0; kk0 < kc; kk0 += 64) {
        const int kbase = k0 + kk0;
        #pragma unroll
        for (int c = 0; c < 2; c++) {
            const int row = c * 32 + arow;
            const int cs = (achk + (row & 7)) & 7;        // skewed src chunk
            gload16(A + (size_t)(m0 + row) * lda + kbase + cs * 8,
                    (char*)As + c * 4096 + tid * 16);
            gload16(Bz + (size_t)(n0 + row) * ldb + kbase + cs * 8,
                    (char*)Bs + c * 4096 + tid * 16);
            if constexpr (GATED)
                gload16(Bz + (size_t)(gate_off_rows + n0 + row) * ldb + kbase + cs * 8,
                        (char*)Us + c * 4096 + tid * 16);
        }
        __syncthreads();

        short8 af[2][2], bfr[2][2];
        #pragma unroll
        for (int mf = 0; mf < 2; mf++)
            #pragma unroll
            for (int kk = 0; kk < 2; kk++) {
                const int r = wr + mf * 16 + lrow;
                const int sl = ((kk * 4 + lg) - (r & 7)) & 7;
                af[mf][kk] = *reinterpret_cast<const short8*>(
                    (const char*)As + r * 128 + sl * 16);
            }
        #pragma unroll
        for (int nf = 0; nf < 2; nf++)
            #pragma unroll
            for (int kk = 0; kk < 2; kk++) {
                const int n = wc + nf * 16 + lrow;
                const int sl = ((kk * 4 + lg) - (n & 7)) & 7;
                bfr[nf][kk] = *reinterpret_cast<const short8*>(
                    (const char*)Bs + n * 128 + sl * 16);
            }
        #pragma unroll
        for (int mf = 0; mf < 2; mf++)
            #pragma unroll
            for (int nf = 0; nf < 2; nf++)
                #pragma unroll
                for (int kk = 0; kk < 2; kk++)
                    accg[mf][nf] = __builtin_amdgcn_mfma_f32_16x16x32_bf16(
                        af[mf][kk], bfr[nf][kk], accg[mf][nf], 0, 0, 0);
        if constexpr (GATED) {
            short8 uf[2][2];
            #pragma unroll
            for (int nf = 0; nf < 2; nf++)
                #pragma unroll
                for (int kk = 0; kk < 2; kk++) {
                    const int n = wc + nf * 16 + lrow;
                    const int sl = ((kk * 4 + lg) - (n & 7)) & 7;
                    uf[nf][kk] = *reinterpret_cast<const short8*>(
                        (const char*)Us + n * 128 + sl * 16);
                }
            #pragma unroll
            for (int mf = 0; mf < 2; mf++)
                #pragma unroll
                for (int nf = 0; nf < 2; nf++)
                    #pragma unroll
                    for (int kk = 0; kk < 2; kk++)
                        accu[mf][nf] = __builtin_amdgcn_mfma_f32_16x16x32_bf16(
                            af[mf][kk], uf[nf][kk], accu[mf][nf], 0, 0, 0);
        }
        __syncthreads();
    }

    // epilogue — C/D layout: col = lane&15, row = (lane>>4)*4 + j
    const int r4 = (lane >> 4) * 4;
    const int cl = lane & 15;
    const int ccol = z * c_z_col;
    #pragma unroll
    for (int mf = 0; mf < 2; mf++) {
        #pragma unroll
        for (int nf = 0; nf < 2; nf++) {
            #pragma unroll
            for (int j = 0; j < 4; j++) {
                const int row = m0 + wr + mf * 16 + r4 + j;
                const int col = ccol + n0 + wc + nf * 16 + cl;
                if constexpr (GATED) {
                    const float g = accg[mf][nf][j];
                    const float u = accu[mf][nf][j];
                    const float sv =
                        scale ? scale[(size_t)row * scale_stride + z] : 1.0f;
                    const float h = (g / (1.0f + __expf(-g))) * u * sv;
                    C16[(size_t)row * ldc + col] = f2bf(h);
                } else if (atomic_flag) {
                    atomicAdd(&Cf[(size_t)row * ldc + col], accg[mf][nf][j]);
                } else {
                    Cf[(size_t)row * ldc + col] = accg[mf][nf][j];
                }
            }
        }
    }
}

// ---------------------------------------------------------------------------
// RoPE + bf16 pack: Qb [16][T][64] (scaled by D^-0.5) and Kb [4][T][64]
// ---------------------------------------------------------------------------
__global__ __launch_bounds__(256) void rope_pack_kernel(
    const float* __restrict__ qkv, const int* __restrict__ positions,
    ushort* __restrict__ Qb, ushort* __restrict__ Kb)
{
    const int t = blockIdx.x;
    const float pos = (float)positions[t];
    for (int item = threadIdx.x; item < (kNQ + kNKV) * 32; item += 256) {
        const int head = item >> 5;
        const int i = item & 31;
        const float inv_freq = powf(10000.0f, -(float)i * (1.0f / 32.0f));
        const float f = pos * inv_freq;
        float sv, cv;
        sincosf(f, &sv, &cv);
        const size_t off = (size_t)t * kQKV + head * kD;
        const float x1 = qkv[off + i];
        const float x2 = qkv[off + 32 + i];
        const float r1 = x1 * cv - x2 * sv;
        const float r2 = x2 * cv + x1 * sv;
        if (head < kNQ) {
            ushort* q = Qb + ((size_t)head * kT + t) * kD;
            q[i] = f2bf(r1 * 0.125f);
            q[i + 32] = f2bf(r2 * 0.125f);
        } else {
            ushort* k = Kb + ((size_t)(head - kNQ) * kT + t) * kD;
            k[i] = f2bf(r1);
            k[i + 32] = f2bf(r2);
        }
    }
}

// ---------------------------------------------------------------------------
// Router: logits = h32 @ gate_w, softmax, top-2 -> combine (T x 8)
// ---------------------------------------------------------------------------
__global__ __launch_bounds__(64) void gate_topk_kernel(
    const float* __restrict__ h, const float* __restrict__ gate_w,
    float* __restrict__ combine)
{
    const int t = blockIdx.x;
    const int lane = threadIdx.x;
    float acc[kE] = {};
    for (int i = lane; i < kH; i += 64) {
        const float xv = h[(size_t)t * kH + i];
        const float* gw = gate_w + (size_t)i * kE;
        #pragma unroll
        for (int e = 0; e < kE; e++) acc[e] += xv * gw[e];
    }
    #pragma unroll
    for (int e = 0; e < kE; e++) {
        #pragma unroll
        for (int off = 32; off > 0; off >>= 1) acc[e] += __shfl_down(acc[e], off);
    }
    if (lane == 0) {
        float mx = acc[0];
        #pragma unroll
        for (int e = 1; e < kE; e++) mx = fmaxf(mx, acc[e]);
        float p[kE];
        float s = 0.0f;
        #pragma unroll
        for (int e = 0; e < kE; e++) { p[e] = expf(acc[e] - mx); s += p[e]; }
        const float invs = 1.0f / s;
        #pragma unroll
        for (int e = 0; e < kE; e++) p[e] *= invs;
        int i1 = 0;
        #pragma unroll
        for (int e = 1; e < kE; e++) if (p[e] > p[i1]) i1 = e;
        int i2 = (i1 == 0) ? 1 : 0;
        #pragma unroll
        for (int e = 0; e < kE; e++) if (e != i1 && p[e] > p[i2]) i2 = e;
        float outv[kE];
        #pragma unroll
        for (int e = 0; e < kE; e++) outv[e] = 0.0f;
        outv[i1] = p[i1];
        outv[i2] = p[i2];
        #pragma unroll
        for (int e = 0; e < kE; e++) combine[(size_t)t * kE + e] = outv[e];
    }
}

// ---------------------------------------------------------------------------
// MFMA flash attention (XOR-swizzled LDS, S^T=mfma(K,Q)) — unchanged
// ---------------------------------------------------------------------------
__global__ __launch_bounds__(256) void attn_mfma_kernel(
    const ushort* __restrict__ Qb, const ushort* __restrict__ Kb,
    const ushort* __restrict__ Vt, ushort* __restrict__ attn_o)
{
    __shared__ __align__(16) ushort Qs[64 * 64];
    __shared__ __align__(16) ushort Ks[64 * 64];
    __shared__ __align__(16) ushort Vs[64 * 64];
    __shared__ __align__(16) ushort Ps[64 * 64];
    const int tid = threadIdx.x;
    const int qb = blockIdx.x * 64;
    const int hq = blockIdx.y;
    const int kvh = hq >> 2;
    const int lane = tid & 63;
    const int wave = tid >> 6;
    const int lrow = lane & 15;
    const int g = lane >> 4;
    const int srow = tid >> 3;
    const int sx = tid & 7;
    const ushort* Qg = Qb + ((size_t)hq * kT + qb) * kD;
    const ushort* Kg = Kb + (size_t)kvh * kT * kD;
    const ushort* Vg = Vt + (size_t)kvh * kD * kT;
    const int xr = (lrow & 7) << 4;

    #pragma unroll
    for (int c = 0; c < 2; c++) {
        const int row = c * 32 + srow;
        gload16(Qg + (size_t)row * kD + ((sx ^ (row & 7)) * 8),
                (char*)Qs + c * 4096 + tid * 16);
    }
    __syncthreads();
    short8 qf[2];
    #pragma unroll
    for (int kk = 0; kk < 2; kk++)
        qf[kk] = *reinterpret_cast<const short8*>(
            (const char*)Qs + (16 * wave + lrow) * 128 + ((kk * 64 + g * 16) ^ xr));

    f32x4 oacc[4] = {};
    float mrow = -1e30f, lsum = 0.0f;

    for (int s0 = 0; s0 <= qb; s0 += 64) {
        __syncthreads();
        #pragma unroll
        for (int c = 0; c < 2; c++) {
            const int row = c * 32 + srow;
            gload16(Kg + (size_t)(s0 + row) * kD + ((sx ^ (row & 7)) * 8),
                    (char*)Ks + c * 4096 + tid * 16);
            gload16(Vg + (size_t)row * kT + s0 + ((sx ^ (row & 7)) * 8),
                    (char*)Vs + c * 4096 + tid * 16);
        }
        __syncthreads();

        f32x4 sacc[4] = {};
        #pragma unroll
        for (int nf = 0; nf < 4; nf++) {
            #pragma unroll
            for (int kk = 0; kk < 2; kk++) {
                short8 kf = *reinterpret_cast<const short8*>(
                    (const char*)Ks + (nf * 16 + lrow) * 128 + ((kk * 64 + g * 16) ^ xr));
                sacc[nf] = __builtin_amdgcn_mfma_f32_16x16x32_bf16(
                    kf, qf[kk], sacc[nf], 0, 0, 0);
            }
        }

        const bool diag = (s0 == qb);
        float pv[16];
        float mloc = -1e30f;
        #pragma unroll
        for (int nf = 0; nf < 4; nf++)
            #pragma unroll
            for (int j = 0; j < 4; j++) {
                float s = sacc[nf][j];
                if (diag && (nf * 16 + g * 4 + j > 16 * wave + lrow)) s = -1e30f;
                pv[nf * 4 + j] = s;
                mloc = fmaxf(mloc, s);
            }
        mloc = fmaxf(mloc, __shfl_xor(mloc, 16));
        mloc = fmaxf(mloc, __shfl_xor(mloc, 32));
        const float mnew = fmaxf(mrow, mloc);
        const float alpha = __expf(mrow - mnew);
        float psum = 0.0f;
        #pragma unroll
        for (int j = 0; j < 16; j++) { pv[j] = __expf(pv[j] - mnew); psum += pv[j]; }
        psum += __shfl_xor(psum, 16);
        psum += __shfl_xor(psum, 32);
        lsum = lsum * alpha + psum;
        mrow = mnew;

        const int prow = 16 * wave + lrow;
        #pragma unroll
        for (int nf = 0; nf < 4; nf++)
            #pragma unroll
            for (int jp = 0; jp < 2; jp++) {
                uint32_t pk = (uint32_t)f2bf(pv[nf * 4 + jp * 2]) |
                              ((uint32_t)f2bf(pv[nf * 4 + jp * 2 + 1]) << 16);
                *reinterpret_cast<uint32_t*>(
                    (char*)Ps + prow * 128 + ((nf * 32 + g * 8 + jp * 4) ^ xr)) = pk;
            }

        float aj[4];
        #pragma unroll
        for (int j = 0; j < 4; j++) aj[j] = __shfl(alpha, g * 4 + j);
        #pragma unroll
        for (int nf = 0; nf < 4; nf++)
            #pragma unroll
            for (int j = 0; j < 4; j++) oacc[nf][j] *= aj[j];

        short8 paf[2];
        #pragma unroll
        for (int kk = 0; kk < 2; kk++)
            paf[kk] = *reinterpret_cast<const short8*>(
                (const char*)Ps + prow * 128 + ((kk * 64 + g * 16) ^ xr));
        #pragma unroll
        for (int nf = 0; nf < 4; nf++)
            #pragma unroll
            for (int kk = 0; kk < 2; kk++) {
                short8 vf = *reinterpret_cast<const short8*>(
                    (const char*)Vs + (nf * 16 + lrow) * 128 + ((kk * 64 + g * 16) ^ xr));
                oacc[nf] = __builtin_amdgcn_mfma_f32_16x16x32_bf16(
                    paf[kk], vf, oacc[nf], 0, 0, 0);
            }
    }

    float lj[4];
    #pragma unroll
    for (int j = 0; j < 4; j++) lj[j] = 1.0f / __shfl(lsum, g * 4 + j);
    #pragma unroll
    for (int nf = 0; nf < 4; nf++)
        #pragma unroll
        for (int j = 0; j < 4; j++) {
            const int trow = qb + 16 * wave + g * 4 + j;
            attn_o[(size_t)trow * (kNQ * kD) + hq * kD + nf * 16 + lrow] =
                f2bf(oacc[nf][j] * lj[j]);
        }
}

__global__ __launch_bounds__(256) void final_out_kernel(
    const float* __restrict__ mlp, const float* __restrict__ shortcut,
    const float* __restrict__ r, float* __restrict__ out)
{
    const int i = blockIdx.x * 256 + threadIdx.x;
    float4 a = reinterpret_cast<const float4*>(mlp)[i];
    float4 b = reinterpret_cast<const float4*>(shortcut)[i];
    reinterpret_cast<float4*>(out)[i] =
        make_float4(a.x + b.x, a.y + b.y, a.z + b.z, a.w + b.w);
    reinterpret_cast<float4*>(out + (size_t)kT * kH)[i] =
        reinterpret_cast<const float4*>(r)[i];
}

}  // namespace

extern "C" void kernel_launch(void* const* d_in, const int* in_sizes, int n_in,
                              void* d_out, int out_size, void* d_ws, size_t ws_size,
                              hipStream_t stream) {
    (void)in_sizes; (void)n_in; (void)out_size; (void)ws_size;
    const float* hidden   = (const float*)d_in[0];
    const float* residual = (const float*)d_in[1];
    const int*   positions= (const int*)d_in[2];
    const float* ln0_w    = (const float*)d_in[3];
    const float* pa0_w    = (const float*)d_in[4];
    const float* ln1_w    = (const float*)d_in[5];
    const float* pa1_w    = (const float*)d_in[6];
    const float* qkv0_w   = (const float*)d_in[7];
    const float* o0_w     = (const float*)d_in[8];
    const float* qkv1_w   = (const float*)d_in[9];
    const float* o1_w     = (const float*)d_in[10];
    const float* gu0_w    = (const float*)d_in[11];
    const float* dn0_w    = (const float*)d_in[12];
    const float* gu1_w    = (const float*)d_in[13];
    const float* dn1_w    = (const float*)d_in[14];
    const float* gate_w   = (const float*)d_in[15];
    const float* w13      = (const float*)d_in[16];
    const float* w2       = (const float*)d_in[17];
    float* out_h = (float*)d_out;

    char* wsb = (char*)d_ws;
    float*  r_buf   = (float*)(wsb + (0ull  << 20));   // 4 MB
    float*  h32     = (float*)(wsb + (4ull  << 20));   // 4 MB
    float*  t0_buf  = (float*)(wsb + (8ull  << 20));   // 4 MB
    float*  qkv_buf = (float*)(wsb + (12ull << 20));   // 6 MB
    float*  sc_buf  = (float*)(wsb + (18ull << 20));   // 4 MB
    float*  cb_buf  = (float*)(wsb + (22ull << 20));   // 32 KB
    ushort* h16     = (ushort*)(wsb + (23ull << 20));  // 2 MB
    ushort* ao16    = (ushort*)(wsb + (25ull << 20));  // 2 MB
    ushort* he16    = (ushort*)(wsb + (27ull << 20));  // 8 MB
    ushort* wT      = (ushort*)(wsb + (35ull << 20));  // 16 MB (ends 51 MB)
    // attn bf16 buffers alias wT tail (only live while wT holds qkv_w^T, 3MB)
    ushort* Qb      = (ushort*)(wsb + (40ull << 20));  // 2 MB
    ushort* Kb      = (ushort*)(wsb + (42ull << 20));  // 0.5 MB
    ushort* VtG     = (ushort*)(wsb + (43ull << 20));  // 0.5 MB

    auto transp = [&](const float* W, int R, int Cn, int nz, long zs) {
        transpose_bf16_kernel<<<dim3(Cn / 64, R / 64, nz), 256, 0, stream>>>(
            W, wT, R, Cn, Cn, zs, zs);
    };
    // C = A(bf16) @ wT^T ; split-K via nz/kzoff + f32 atomics
    auto gemm_f32 = [&](const ushort* A, float* C, int N, int lda_,
                        int ldb_, int ldc_, int nz, int kc, int kzoff, int atomic) {
        mgemm_kernel<false><<<dim3(N / 64, kT / 64, nz), 256, 0, stream>>>(
            A, wT, C, nullptr, nullptr, lda_, ldb_, ldc_, kc,
            0, 0, 0, kzoff, 0, atomic);
    };
    auto attention = [&](const float* qkv_w, const float* o_w) {
        transp(qkv_w, kH, kQKV, 1, 0);
        gemm_f32(h16, qkv_buf, kQKV, kH, kH, kQKV, 1, kH, 0, 0);
        rope_pack_kernel<<<kT, 256, 0, stream>>>(qkv_buf, positions, Qb, Kb);
        transpose_bf16_kernel<<<dim3(1, kT / 64, kNKV), 256, 0, stream>>>(
            qkv_buf + (kNQ + kNKV) * kD, VtG, kT, kD, kQKV, kD, (long)kD * kT);
        attn_mfma_kernel<<<dim3(kT / 64, kNQ), 256, 0, stream>>>(Qb, Kb, VtG, ao16);
        transp(o_w, kNQ * kD, kH, 1, 0);
        hipMemsetAsync(t0_buf, 0, (size_t)kT * kH * 4, stream);
        gemm_f32(ao16, t0_buf, kH, kNQ * kD, kNQ * kD, kH, 2, 512, 512, 1);
    };
    auto dense_mlp = [&](const float* gu_w, const float* dn_w) {
        transp(gu_w, kH, 2 * kIDense, 1, 0);
        mgemm_kernel<true><<<dim3(kIDense / 64, kT / 64, 1), 256, 0, stream>>>(
            h16, wT, nullptr, he16, nullptr, kH, kH, kIDense, kH,
            kIDense, 0, 0, 0, 0, 0);
        transp(dn_w, kIDense, kH, 1, 0);
        hipMemsetAsync(t0_buf, 0, (size_t)kT * kH * 4, stream);
        gemm_f32(he16, t0_buf, kH, kIDense, kIDense, kH, 4, 1024, 1024, 1);
    };

    // h, r = add_rmsnorm(hidden, residual, ln0)
    add_rmsnorm_kernel<<<kT, 256, 0, stream>>>(hidden, residual, ln0_w, h32, h16, r_buf);
    // h = attention0(h) -> t0
    attention(qkv0_w, o0_w);
    // h, r = add_rmsnorm(t0, r, pa0)
    add_rmsnorm_kernel<<<kT, 256, 0, stream>>>(t0_buf, r_buf, pa0_w, h32, h16, r_buf);
    // shortcut = moe(h)
    gate_topk_kernel<<<kT, 64, 0, stream>>>(h32, gate_w, cb_buf);
    transp(w13, kH, 2 * kIMoe, kE, (long)kH * 2 * kIMoe);
    mgemm_kernel<true><<<dim3(kIMoe / 64, kT / 64, kE), 256, 0, stream>>>(
        h16, wT, nullptr, he16, cb_buf, kH, kH, kIDense, kH,
        kIMoe, (long)kH * 2 * kIMoe, kIMoe, 0, kE, 0);
    transp(w2, kE * kIMoe, kH, 1, 0);
    hipMemsetAsync(sc_buf, 0, (size_t)kT * kH * 4, stream);
    gemm_f32(he16, sc_buf, kH, kIDense, kIDense, kH, 4, 1024, 1024, 1);
    // h = dense_mlp0(h) -> t0
    dense_mlp(gu0_w, dn0_w);
    // h, r = add_rmsnorm(t0, r, ln1)
    add_rmsnorm_kernel<<<kT, 256, 0, stream>>>(t0_buf, r_buf, ln1_w, h32, h16, r_buf);
    // h = attention1(h) -> t0
    attention(qkv1_w, o1_w);
    // h, r = add_rmsnorm(t0, r, pa1)
    add_rmsnorm_kernel<<<kT, 256, 0, stream>>>(t0_buf, r_buf, pa1_w, h32, h16, r_buf);
    // h = dense_mlp1(h) -> t0
    dense_mlp(gu1_w, dn1_w);
    // out = (t0 + shortcut, r)
    final_out_kernel<<<(kT * kH / 4) / 256, 256, 0, stream>>>(t0_buf, sc_buf, r_buf, out_h);
}